// Round 2
// baseline (4138.954 us; speedup 1.0000x reference)
//
#include <hip/hip_runtime.h>
#include <hip/hip_bf16.h>
#include <cstddef>

#define T_LEN 2048
#define H2 256
#define G4 1024   // 4*H2
#define NLBL 32
#define CLS_TAG 0
#define SEP_TAG 31

// ---------------- helpers ----------------

#if defined(__has_builtin)
#if __has_builtin(__builtin_amdgcn_sdot4)
#define HAS_SDOT4 1
#endif
#if __has_builtin(__builtin_amdgcn_rcpf)
#define HAS_RCPF 1
#endif
#endif

__device__ __forceinline__ int dot4i8(int a, int b, int c) {
#ifdef HAS_SDOT4
    return __builtin_amdgcn_sdot4(a, b, c, false);
#else
    c += (int)((signed char)(a & 0xff))         * (int)((signed char)(b & 0xff));
    c += (int)((signed char)((a >> 8) & 0xff))  * (int)((signed char)((b >> 8) & 0xff));
    c += (int)((signed char)((a >> 16) & 0xff)) * (int)((signed char)((b >> 16) & 0xff));
    c += (int)((signed char)(a >> 24))          * (int)((signed char)(b >> 24));
    return c;
#endif
}

__device__ __forceinline__ float rcpf(float x) {
#ifdef HAS_RCPF
    return __builtin_amdgcn_rcpf(x);
#else
    return 1.0f / x;
#endif
}

__device__ __forceinline__ float sigf(float x) {
    return rcpf(1.0f + __expf(-x));
}

__device__ __forceinline__ float tanhf_(float x) {
    x = fminf(fmaxf(x, -15.0f), 15.0f);
    float e = __expf(2.0f * x);
    return (e - 1.0f) * rcpf(e + 1.0f);
}

// ---------------- kernels ----------------

// 1. gather embeddings: xbuf[t][e] = emb[ids[t]][e]
__global__ __launch_bounds__(256) void gather_k(const int* __restrict__ ids,
                                                const float* __restrict__ emb,
                                                float* __restrict__ xbuf) {
    int t = blockIdx.x;
    int row = ids[t];
    xbuf[(size_t)t * 256 + threadIdx.x] = emb[(size_t)row * 256 + threadIdx.x];
}

// 2. quantize w_hh (per-row symmetric int8). one wave per row.
__global__ __launch_bounds__(256) void quant_w_k(const float* __restrict__ w_hh_f,
                                                 const float* __restrict__ w_hh_b,
                                                 signed char* __restrict__ wq,
                                                 float* __restrict__ srow) {
    int wave = threadIdx.x >> 6, lane = threadIdx.x & 63;
    int rg = blockIdx.x * 4 + wave;              // 0..2047
    int dir = rg >> 10, r = rg & 1023;
    const float* src = (dir ? w_hh_b : w_hh_f) + (size_t)r * H2;
    float4 w4 = ((const float4*)src)[lane];
    float m = fmaxf(fmaxf(fabsf(w4.x), fabsf(w4.y)), fmaxf(fabsf(w4.z), fabsf(w4.w)));
    #pragma unroll
    for (int off = 32; off; off >>= 1) m = fmaxf(m, __shfl_xor(m, off, 64));
    float s = (m > 0.0f) ? m * (1.0f / 127.0f) : 1.0f;
    float inv = rcpf(s);
    int q0 = __float2int_rn(w4.x * inv);
    int q1 = __float2int_rn(w4.y * inv);
    int q2 = __float2int_rn(w4.z * inv);
    int q3 = __float2int_rn(w4.w * inv);
    int packed = (q0 & 255) | ((q1 & 255) << 8) | ((q2 & 255) << 16) | ((q3 & 255) << 24);
    ((int*)wq)[(size_t)rg * 64 + lane] = packed;
    if (lane == 0) srow[rg] = s;                  // w = q * s
}

// 3. quantize h0 (per-direction scale). one wave per direction.
__global__ __launch_bounds__(64) void quant_h0_k(const float* __restrict__ h0,
                                                 int* __restrict__ hq0,
                                                 float* __restrict__ sh0) {
    int dir = blockIdx.x, lane = threadIdx.x;
    float4 h4 = ((const float4*)(h0 + (size_t)dir * H2))[lane];
    float m = fmaxf(fmaxf(fabsf(h4.x), fabsf(h4.y)), fmaxf(fabsf(h4.z), fabsf(h4.w)));
    #pragma unroll
    for (int off = 32; off; off >>= 1) m = fmaxf(m, __shfl_xor(m, off, 64));
    float s = (m > 0.0f) ? m * (1.0f / 127.0f) : 1.0f;
    float inv = rcpf(s);
    int q0 = __float2int_rn(h4.x * inv);
    int q1 = __float2int_rn(h4.y * inv);
    int q2 = __float2int_rn(h4.z * inv);
    int q3 = __float2int_rn(h4.w * inv);
    hq0[dir * 64 + lane] = (q0 & 255) | ((q1 & 255) << 8) | ((q2 & 255) << 16) | ((q3 & 255) << 24);
    if (lane == 0) sh0[dir] = s;
}

// 4. xproj GEMM: xproj[dir][t][n] = x[t]@w_ih_dir[n] + b_dir[n]
__global__ __launch_bounds__(256) void gemm_xproj_k(const float* __restrict__ xbuf,
                                                    const float* __restrict__ w_ih_f,
                                                    const float* __restrict__ w_ih_b,
                                                    const float* __restrict__ b_f,
                                                    const float* __restrict__ b_b,
                                                    float* __restrict__ xproj) {
    __shared__ float As[64][33];
    __shared__ float Bs[64][33];
    int tid = threadIdx.x;
    int t0 = blockIdx.x * 64;
    int n0 = blockIdx.y * 64;     // n in [0,2048)
    int tx = tid & 15, ty = tid >> 4;
    float acc[4][4] = {};
    for (int k0 = 0; k0 < 256; k0 += 32) {
        #pragma unroll
        for (int i = 0; i < 8; ++i) {
            int idx = tid + i * 256;
            int r = idx >> 5, kk = idx & 31;
            As[r][kk] = xbuf[(size_t)(t0 + r) * 256 + k0 + kk];
            int nn = n0 + r;
            const float* wsrc = (nn < 1024) ? (w_ih_f + (size_t)nn * 256)
                                            : (w_ih_b + (size_t)(nn - 1024) * 256);
            Bs[r][kk] = wsrc[k0 + kk];
        }
        __syncthreads();
        #pragma unroll
        for (int kk = 0; kk < 32; ++kk) {
            float a[4], b[4];
            #pragma unroll
            for (int i = 0; i < 4; ++i) a[i] = As[ty * 4 + i][kk];
            #pragma unroll
            for (int j = 0; j < 4; ++j) b[j] = Bs[tx * 4 + j][kk];
            #pragma unroll
            for (int i = 0; i < 4; ++i)
                #pragma unroll
                for (int j = 0; j < 4; ++j) acc[i][j] += a[i] * b[j];
        }
        __syncthreads();
    }
    #pragma unroll
    for (int j = 0; j < 4; ++j) {
        int nn = n0 + tx * 4 + j;
        int dir = nn >> 10, nl = nn & 1023;
        float bias = dir ? b_b[nl] : b_f[nl];
        #pragma unroll
        for (int i = 0; i < 4; ++i) {
            int t = t0 + ty * 4 + i;
            xproj[((size_t)dir * T_LEN + t) * G4 + nl] = acc[i][j] + bias;
        }
    }
}

// 5. LSTM recurrence v2. grid = 2 (dir), block = 256; each thread owns all 4
//    gate rows of one hidden unit -> no z exchange, 1 barrier/step, weights
//    (4 x 256 int8 = 256 VGPRs) resident in registers at 1 wave/SIMD.
__global__ __launch_bounds__(256, 1) void lstm_rec_k(const signed char* __restrict__ wq,
                                                     const float* __restrict__ srow,
                                                     const float* __restrict__ xproj,
                                                     const int* __restrict__ hq0,
                                                     const float* __restrict__ sh0v,
                                                     const float* __restrict__ c0,
                                                     float* __restrict__ hs) {
    const int dir = blockIdx.x;
    const int tid = threadIdx.x;
    __shared__ int4 hq[2][16];     // ping-pong packed int8 hidden state

    int4 wv[4][16];                // gate g row = tid + 256*g
    #pragma unroll
    for (int g = 0; g < 4; ++g) {
        const int4* wrow = (const int4*)(wq + ((size_t)dir * G4 + g * 256 + tid) * H2);
        #pragma unroll
        for (int k = 0; k < 16; ++k) wv[g][k] = wrow[k];
    }
    float sr[4];
    #pragma unroll
    for (int g = 0; g < 4; ++g) sr[g] = srow[dir * G4 + g * 256 + tid];
    float sh = sh0v[dir];
    const float* xp = xproj + (size_t)dir * T_LEN * G4;
    float c = c0[dir * H2 + tid];
    if (tid < 16) hq[0][tid] = ((const int4*)hq0)[dir * 16 + tid];

    const int step = dir ? -1 : 1;
    int t = dir ? (T_LEN - 1) : 0;
    float zx[4];
    #pragma unroll
    for (int g = 0; g < 4; ++g) zx[g] = xp[(size_t)t * G4 + g * 256 + tid];
    __syncthreads();

    for (int s = 0; s < T_LEN; ++s) {
        int tn = (s == T_LEN - 1) ? t : (t + step);
        float zxn[4];                              // prefetch next step's inputs
        #pragma unroll
        for (int g = 0; g < 4; ++g) zxn[g] = xp[(size_t)tn * G4 + g * 256 + tid];

        const int buf = s & 1;
        int acc0 = 0, acc1 = 0, acc2 = 0, acc3 = 0;
        #pragma unroll
        for (int k = 0; k < 16; ++k) {
            int4 hv = hq[buf][k];                  // LDS broadcast read
            acc0 = dot4i8(wv[0][k].x, hv.x, acc0);
            acc1 = dot4i8(wv[1][k].x, hv.x, acc1);
            acc2 = dot4i8(wv[2][k].x, hv.x, acc2);
            acc3 = dot4i8(wv[3][k].x, hv.x, acc3);
            acc0 = dot4i8(wv[0][k].y, hv.y, acc0);
            acc1 = dot4i8(wv[1][k].y, hv.y, acc1);
            acc2 = dot4i8(wv[2][k].y, hv.y, acc2);
            acc3 = dot4i8(wv[3][k].y, hv.y, acc3);
            acc0 = dot4i8(wv[0][k].z, hv.z, acc0);
            acc1 = dot4i8(wv[1][k].z, hv.z, acc1);
            acc2 = dot4i8(wv[2][k].z, hv.z, acc2);
            acc3 = dot4i8(wv[3][k].z, hv.z, acc3);
            acc0 = dot4i8(wv[0][k].w, hv.w, acc0);
            acc1 = dot4i8(wv[1][k].w, hv.w, acc1);
            acc2 = dot4i8(wv[2][k].w, hv.w, acc2);
            acc3 = dot4i8(wv[3][k].w, hv.w, acc3);
        }
        float zi = zx[0] + sr[0] * sh * (float)acc0;
        float zf = zx[1] + sr[1] * sh * (float)acc1;
        float zg = zx[2] + sr[2] * sh * (float)acc2;
        float zo = zx[3] + sr[3] * sh * (float)acc3;
        float ig = sigf(zi), fg = sigf(zf), gg = tanhf_(zg), og = sigf(zo);
        c = fg * c + ig * gg;
        float h = og * tanhf_(c);
        hs[(size_t)t * 512 + dir * H2 + tid] = h;
        int q = __float2int_rn(fminf(fmaxf(h * 127.0f, -127.0f), 127.0f));
        ((signed char*)hq[1 - buf])[tid] = (signed char)q;
        sh = 1.0f / 127.0f;                        // steady-state h scale
        #pragma unroll
        for (int g = 0; g < 4; ++g) zx[g] = zxn[g];
        t = tn;
        __syncthreads();                           // publish hq[1-buf]
    }
}

// 6. logits: [T][32] = hs[T][512] @ w_lin^T + b_lin. grid (256, 2), block 128.
__global__ __launch_bounds__(128) void logits_k(const float* __restrict__ hs,
                                                const float* __restrict__ w_lin,
                                                const float* __restrict__ b_lin,
                                                float* __restrict__ logits) {
    __shared__ float wldT[512][17];   // [k][j] transposed, padded
    __shared__ float hld[8][512];
    int tid = threadIdx.x;
    int t0 = blockIdx.x * 8;
    int n0 = blockIdx.y * 16;
    for (int i = tid; i < 16 * 512; i += 128) {
        int j = i >> 9, k = i & 511;
        wldT[k][j] = w_lin[(size_t)(n0 + j) * 512 + k];
    }
    for (int i = tid; i < 8 * 512; i += 128) {
        int tq = i >> 9, k = i & 511;
        hld[tq][k] = hs[(size_t)(t0 + tq) * 512 + k];
    }
    __syncthreads();
    int j = tid & 15, tq = tid >> 4;
    float acc = b_lin[n0 + j];
    #pragma unroll 8
    for (int k = 0; k < 512; ++k) acc += hld[tq][k] * wldT[k][j];
    logits[(size_t)(t0 + tq) * NLBL + n0 + j] = acc;
}

// 7. gold path score
__global__ __launch_bounds__(256) void gold_k(const float* __restrict__ trans,
                                              const int* __restrict__ target,
                                              const float* __restrict__ logits,
                                              float* __restrict__ gold) {
    __shared__ float red[256];
    int tid = threadIdx.x;
    float s = 0.0f;
    for (int t = tid; t < T_LEN; t += 256) {
        int cur = target[t];
        int prev = (t == 0) ? CLS_TAG : target[t - 1];
        s += trans[cur * NLBL + prev] + logits[(size_t)t * NLBL + cur];
    }
    if (tid == 0) s += trans[SEP_TAG * NLBL + target[T_LEN - 1]];
    red[tid] = s;
    __syncthreads();
    for (int st = 128; st; st >>= 1) {
        if (tid < st) red[tid] += red[tid + st];
        __syncthreads();
    }
    if (tid == 0) gold[0] = red[0];
}

// 8. CRF forward algorithm + final output. 1 block, 1024 threads: tid = n*32+p
__global__ __launch_bounds__(1024) void crf_k(const float* __restrict__ logits,
                                              const float* __restrict__ trans,
                                              const float* __restrict__ gold,
                                              float* __restrict__ out) {
    const int tid = threadIdx.x;
    const int n = tid >> 5, p = tid & 31;
    __shared__ float alpha[2][NLBL];
    float tr = trans[n * NLBL + p];
    if (tid < NLBL) alpha[0][tid] = (tid == CLS_TAG) ? 0.0f : -10000.0f;
    __syncthreads();
    for (int t = 0; t < T_LEN; ++t) {
        float em = logits[(size_t)t * NLBL + n];
        float v = alpha[t & 1][p] + tr;
        float m = v;
        #pragma unroll
        for (int off = 16; off; off >>= 1) m = fmaxf(m, __shfl_xor(m, off, 32));
        float e = __expf(v - m);
        #pragma unroll
        for (int off = 16; off; off >>= 1) e += __shfl_xor(e, off, 32);
        if (p == 0) alpha[(t + 1) & 1][n] = m + __logf(e) + em;
        __syncthreads();
    }
    if (tid < NLBL) {
        float v = alpha[0][tid] + trans[SEP_TAG * NLBL + tid];   // T even -> buf 0
        float m = v;
        #pragma unroll
        for (int off = 16; off; off >>= 1) m = fmaxf(m, __shfl_xor(m, off, 32));
        float e = __expf(v - m);
        #pragma unroll
        for (int off = 16; off; off >>= 1) e += __shfl_xor(e, off, 32);
        if (tid == 0) out[0] = m + __logf(e) - gold[0];
    }
}

// ---------------- launch ----------------

extern "C" void kernel_launch(void* const* d_in, const int* in_sizes, int n_in,
                              void* d_out, int out_size, void* d_ws, size_t ws_size,
                              hipStream_t stream) {
    const int*   ids     = (const int*)d_in[0];
    // d_in[1] attention_mask unused (all ones)
    const int*   target  = (const int*)d_in[2];
    const float* emb     = (const float*)d_in[3];
    const float* w_ih_f  = (const float*)d_in[4];
    const float* w_hh_f  = (const float*)d_in[5];
    const float* b_f     = (const float*)d_in[6];
    const float* w_ih_b  = (const float*)d_in[7];
    const float* w_hh_b  = (const float*)d_in[8];
    const float* b_b     = (const float*)d_in[9];
    const float* w_lin   = (const float*)d_in[10];
    const float* b_lin   = (const float*)d_in[11];
    const float* trans   = (const float*)d_in[12];
    const float* h0      = (const float*)d_in[13];
    const float* c0      = (const float*)d_in[14];
    float* out = (float*)d_out;

    char* ws = (char*)d_ws;
    size_t off = 0;
    float* xbuf   = (float*)(ws + off); off += (size_t)T_LEN * 256 * 4;       // 2 MB
    float* xproj  = (float*)(ws + off); off += (size_t)2 * T_LEN * G4 * 4;    // 16 MB
    float* hs     = (float*)(ws + off); off += (size_t)T_LEN * 512 * 4;       // 4 MB
    float* logits = (float*)(ws + off); off += (size_t)T_LEN * NLBL * 4;      // 256 KB
    float* srow   = (float*)(ws + off); off += (size_t)2 * G4 * 4;            // 8 KB
    float* sh0v   = (float*)(ws + off); off += 16;
    float* gold   = (float*)(ws + off); off += 16;
    int*   hq0    = (int*)(ws + off);   off += (size_t)2 * 64 * 4;
    signed char* wq = (signed char*)(ws + off); off += (size_t)2 * G4 * H2;   // 512 KB

    gather_k<<<T_LEN, 256, 0, stream>>>(ids, emb, xbuf);
    quant_w_k<<<512, 256, 0, stream>>>(w_hh_f, w_hh_b, wq, srow);
    quant_h0_k<<<2, 64, 0, stream>>>(h0, hq0, sh0v);
    gemm_xproj_k<<<dim3(32, 32), 256, 0, stream>>>(xbuf, w_ih_f, w_ih_b, b_f, b_b, xproj);
    lstm_rec_k<<<2, 256, 0, stream>>>(wq, srow, xproj, hq0, sh0v, c0, hs);
    logits_k<<<dim3(256, 2), 128, 0, stream>>>(hs, w_lin, b_lin, logits);
    gold_k<<<1, 256, 0, stream>>>(trans, target, logits, gold);
    crf_k<<<1, 1024, 0, stream>>>(logits, trans, gold, out);
}

// Round 3
// 2172.029 us; speedup vs baseline: 1.9056x; 1.9056x over previous
//
#include <hip/hip_runtime.h>
#include <hip/hip_bf16.h>
#include <cstddef>

#define T_LEN 2048
#define H2 256
#define G4 1024   // 4*H2
#define NLBL 32
#define CLS_TAG 0
#define SEP_TAG 31

// ---------------- helpers ----------------

#if defined(__has_builtin)
#if __has_builtin(__builtin_amdgcn_sdot4)
#define HAS_SDOT4 1
#endif
#if __has_builtin(__builtin_amdgcn_rcpf)
#define HAS_RCPF 1
#endif
#endif

__device__ __forceinline__ int dot4i8(int a, int b, int c) {
#ifdef HAS_SDOT4
    return __builtin_amdgcn_sdot4(a, b, c, false);
#else
    c += (int)((signed char)(a & 0xff))         * (int)((signed char)(b & 0xff));
    c += (int)((signed char)((a >> 8) & 0xff))  * (int)((signed char)((b >> 8) & 0xff));
    c += (int)((signed char)((a >> 16) & 0xff)) * (int)((signed char)((b >> 16) & 0xff));
    c += (int)((signed char)(a >> 24))          * (int)((signed char)(b >> 24));
    return c;
#endif
}

__device__ __forceinline__ float rcpf(float x) {
#ifdef HAS_RCPF
    return __builtin_amdgcn_rcpf(x);
#else
    return 1.0f / x;
#endif
}

__device__ __forceinline__ float sigf(float x) {
    return rcpf(1.0f + __expf(-x));
}

__device__ __forceinline__ float tanhf_(float x) {
    x = fminf(fmaxf(x, -15.0f), 15.0f);
    float e = __expf(2.0f * x);
    return (e - 1.0f) * rcpf(e + 1.0f);
}

// ---------------- kernels ----------------

// 1. gather embeddings
__global__ __launch_bounds__(256) void gather_k(const int* __restrict__ ids,
                                                const float* __restrict__ emb,
                                                float* __restrict__ xbuf) {
    int t = blockIdx.x;
    int row = ids[t];
    xbuf[(size_t)t * 256 + threadIdx.x] = emb[(size_t)row * 256 + threadIdx.x];
}

// 2. quantize w_hh (per-row symmetric int8). one wave per row.
__global__ __launch_bounds__(256) void quant_w_k(const float* __restrict__ w_hh_f,
                                                 const float* __restrict__ w_hh_b,
                                                 signed char* __restrict__ wq,
                                                 float* __restrict__ srow) {
    int wave = threadIdx.x >> 6, lane = threadIdx.x & 63;
    int rg = blockIdx.x * 4 + wave;              // 0..2047
    int dir = rg >> 10, r = rg & 1023;
    const float* src = (dir ? w_hh_b : w_hh_f) + (size_t)r * H2;
    float4 w4 = ((const float4*)src)[lane];
    float m = fmaxf(fmaxf(fabsf(w4.x), fabsf(w4.y)), fmaxf(fabsf(w4.z), fabsf(w4.w)));
    #pragma unroll
    for (int off = 32; off; off >>= 1) m = fmaxf(m, __shfl_xor(m, off, 64));
    float s = (m > 0.0f) ? m * (1.0f / 127.0f) : 1.0f;
    float inv = rcpf(s);
    int q0 = __float2int_rn(w4.x * inv);
    int q1 = __float2int_rn(w4.y * inv);
    int q2 = __float2int_rn(w4.z * inv);
    int q3 = __float2int_rn(w4.w * inv);
    int packed = (q0 & 255) | ((q1 & 255) << 8) | ((q2 & 255) << 16) | ((q3 & 255) << 24);
    ((int*)wq)[(size_t)rg * 64 + lane] = packed;
    if (lane == 0) srow[rg] = s;
}

// 3. quantize h0
__global__ __launch_bounds__(64) void quant_h0_k(const float* __restrict__ h0,
                                                 int* __restrict__ hq0,
                                                 float* __restrict__ sh0) {
    int dir = blockIdx.x, lane = threadIdx.x;
    float4 h4 = ((const float4*)(h0 + (size_t)dir * H2))[lane];
    float m = fmaxf(fmaxf(fabsf(h4.x), fabsf(h4.y)), fmaxf(fabsf(h4.z), fabsf(h4.w)));
    #pragma unroll
    for (int off = 32; off; off >>= 1) m = fmaxf(m, __shfl_xor(m, off, 64));
    float s = (m > 0.0f) ? m * (1.0f / 127.0f) : 1.0f;
    float inv = rcpf(s);
    int q0 = __float2int_rn(h4.x * inv);
    int q1 = __float2int_rn(h4.y * inv);
    int q2 = __float2int_rn(h4.z * inv);
    int q3 = __float2int_rn(h4.w * inv);
    hq0[dir * 64 + lane] = (q0 & 255) | ((q1 & 255) << 8) | ((q2 & 255) << 16) | ((q3 & 255) << 24);
    if (lane == 0) sh0[dir] = s;
}

// 4. xproj GEMM
__global__ __launch_bounds__(256) void gemm_xproj_k(const float* __restrict__ xbuf,
                                                    const float* __restrict__ w_ih_f,
                                                    const float* __restrict__ w_ih_b,
                                                    const float* __restrict__ b_f,
                                                    const float* __restrict__ b_b,
                                                    float* __restrict__ xproj) {
    __shared__ float As[64][33];
    __shared__ float Bs[64][33];
    int tid = threadIdx.x;
    int t0 = blockIdx.x * 64;
    int n0 = blockIdx.y * 64;
    int tx = tid & 15, ty = tid >> 4;
    float acc[4][4] = {};
    for (int k0 = 0; k0 < 256; k0 += 32) {
        #pragma unroll
        for (int i = 0; i < 8; ++i) {
            int idx = tid + i * 256;
            int r = idx >> 5, kk = idx & 31;
            As[r][kk] = xbuf[(size_t)(t0 + r) * 256 + k0 + kk];
            int nn = n0 + r;
            const float* wsrc = (nn < 1024) ? (w_ih_f + (size_t)nn * 256)
                                            : (w_ih_b + (size_t)(nn - 1024) * 256);
            Bs[r][kk] = wsrc[k0 + kk];
        }
        __syncthreads();
        #pragma unroll
        for (int kk = 0; kk < 32; ++kk) {
            float a[4], b[4];
            #pragma unroll
            for (int i = 0; i < 4; ++i) a[i] = As[ty * 4 + i][kk];
            #pragma unroll
            for (int j = 0; j < 4; ++j) b[j] = Bs[tx * 4 + j][kk];
            #pragma unroll
            for (int i = 0; i < 4; ++i)
                #pragma unroll
                for (int j = 0; j < 4; ++j) acc[i][j] += a[i] * b[j];
        }
        __syncthreads();
    }
    #pragma unroll
    for (int j = 0; j < 4; ++j) {
        int nn = n0 + tx * 4 + j;
        int dir = nn >> 10, nl = nn & 1023;
        float bias = dir ? b_b[nl] : b_f[nl];
        #pragma unroll
        for (int i = 0; i < 4; ++i) {
            int t = t0 + ty * 4 + i;
            xproj[((size_t)dir * T_LEN + t) * G4 + nl] = acc[i][j] + bias;
        }
    }
}

// 5. LSTM recurrence v3. grid = 2, block = 512; thread owns rows tid and
//    tid+512 (128 VGPRs of weights -> fits under the 256-VGPR arch cap,
//    2 waves/SIMD for TLP). Halves LDS broadcast op count vs v1.
__global__ __launch_bounds__(512, 2) void lstm_rec_k(const signed char* __restrict__ wq,
                                                     const float* __restrict__ srow,
                                                     const float* __restrict__ xproj,
                                                     const int* __restrict__ hq0,
                                                     const float* __restrict__ sh0v,
                                                     const float* __restrict__ c0,
                                                     float* __restrict__ hs) {
    const int dir = blockIdx.x;
    const int tid = threadIdx.x;          // 0..511
    __shared__ int4 hq[2][16];            // ping-pong packed int8 hidden state
    __shared__ float zbuf[G4];

    int4 wv0[16], wv1[16];
    {
        const int4* wr0 = (const int4*)(wq + ((size_t)dir * G4 + tid) * H2);
        const int4* wr1 = (const int4*)(wq + ((size_t)dir * G4 + tid + 512) * H2);
        #pragma unroll
        for (int k = 0; k < 16; ++k) { wv0[k] = wr0[k]; wv1[k] = wr1[k]; }
    }
    float sr0 = srow[dir * G4 + tid];
    float sr1 = srow[dir * G4 + tid + 512];
    float sh = sh0v[dir];
    const float* xp = xproj + (size_t)dir * T_LEN * G4;
    float c = (tid < H2) ? c0[dir * H2 + tid] : 0.0f;
    if (tid < 16) hq[0][tid] = ((const int4*)hq0)[dir * 16 + tid];

    // xproj prefetch pipeline, depth 2
    int ts0 = dir ? (T_LEN - 1) : 0;
    int ts1 = dir ? (T_LEN - 2) : 1;
    float za0 = xp[(size_t)ts0 * G4 + tid];
    float za1 = xp[(size_t)ts0 * G4 + tid + 512];
    float zb0 = xp[(size_t)ts1 * G4 + tid];
    float zb1 = xp[(size_t)ts1 * G4 + tid + 512];
    __syncthreads();

    for (int s = 0; s < T_LEN; ++s) {
        int ts = dir ? (T_LEN - 1 - s) : s;
        int tp = (s + 2 < T_LEN) ? (dir ? (T_LEN - 3 - s) : (s + 2)) : ts;
        float zc0 = xp[(size_t)tp * G4 + tid];            // prefetch s+2
        float zc1 = xp[(size_t)tp * G4 + tid + 512];

        const int buf = s & 1;
        int acc0 = 0, acc1 = 0;
        #pragma unroll
        for (int k = 0; k < 16; ++k) {
            int4 hv = hq[buf][k];                          // broadcast read
            acc0 = dot4i8(wv0[k].x, hv.x, acc0);
            acc1 = dot4i8(wv1[k].x, hv.x, acc1);
            acc0 = dot4i8(wv0[k].y, hv.y, acc0);
            acc1 = dot4i8(wv1[k].y, hv.y, acc1);
            acc0 = dot4i8(wv0[k].z, hv.z, acc0);
            acc1 = dot4i8(wv1[k].z, hv.z, acc1);
            acc0 = dot4i8(wv0[k].w, hv.w, acc0);
            acc1 = dot4i8(wv1[k].w, hv.w, acc1);
        }
        zbuf[tid]       = za0 + sr0 * sh * (float)acc0;
        zbuf[tid + 512] = za1 + sr1 * sh * (float)acc1;
        __syncthreads();
        if (tid < H2) {
            float zi = zbuf[tid];
            float zf = zbuf[H2 + tid];
            float zg = zbuf[2 * H2 + tid];
            float zo = zbuf[3 * H2 + tid];
            float ig = sigf(zi), fg = sigf(zf), gg = tanhf_(zg), og = sigf(zo);
            c = fg * c + ig * gg;
            float h = og * tanhf_(c);
            hs[(size_t)ts * 512 + dir * H2 + tid] = h;
            int q = __float2int_rn(fminf(fmaxf(h * 127.0f, -127.0f), 127.0f));
            ((signed char*)hq[1 - buf])[tid] = (signed char)q;
        }
        sh = 1.0f / 127.0f;
        za0 = zb0; za1 = zb1; zb0 = zc0; zb1 = zc1;
        __syncthreads();                                   // publish hq[1-buf]
    }
}

// 6. logits
__global__ __launch_bounds__(128) void logits_k(const float* __restrict__ hs,
                                                const float* __restrict__ w_lin,
                                                const float* __restrict__ b_lin,
                                                float* __restrict__ logits) {
    __shared__ float wldT[512][17];
    __shared__ float hld[8][512];
    int tid = threadIdx.x;
    int t0 = blockIdx.x * 8;
    int n0 = blockIdx.y * 16;
    for (int i = tid; i < 16 * 512; i += 128) {
        int j = i >> 9, k = i & 511;
        wldT[k][j] = w_lin[(size_t)(n0 + j) * 512 + k];
    }
    for (int i = tid; i < 8 * 512; i += 128) {
        int tq = i >> 9, k = i & 511;
        hld[tq][k] = hs[(size_t)(t0 + tq) * 512 + k];
    }
    __syncthreads();
    int j = tid & 15, tq = tid >> 4;
    float acc = b_lin[n0 + j];
    #pragma unroll 8
    for (int k = 0; k < 512; ++k) acc += hld[tq][k] * wldT[k][j];
    logits[(size_t)(t0 + tq) * NLBL + n0 + j] = acc;
}

// 7. gold path score
__global__ __launch_bounds__(256) void gold_k(const float* __restrict__ trans,
                                              const int* __restrict__ target,
                                              const float* __restrict__ logits,
                                              float* __restrict__ gold) {
    __shared__ float red[256];
    int tid = threadIdx.x;
    float s = 0.0f;
    for (int t = tid; t < T_LEN; t += 256) {
        int cur = target[t];
        int prev = (t == 0) ? CLS_TAG : target[t - 1];
        s += trans[cur * NLBL + prev] + logits[(size_t)t * NLBL + cur];
    }
    if (tid == 0) s += trans[SEP_TAG * NLBL + target[T_LEN - 1]];
    red[tid] = s;
    __syncthreads();
    for (int st = 128; st; st >>= 1) {
        if (tid < st) red[tid] += red[tid + st];
        __syncthreads();
    }
    if (tid == 0) gold[0] = red[0];
}

// 8a. CRF tree level 0: block b computes log-matmul chain of steps [8b, 8b+8).
//     M_t[n,p] = trans[n,p] + e[t,n];  R' = M ∘ R with (A∘B)[n,p]=lse_k(A[n,k]+B[k,p]).
__global__ __launch_bounds__(1024) void crf_chain0_k(const float* __restrict__ logits,
                                                     const float* __restrict__ trans,
                                                     float* __restrict__ mats) {
    const int tid = threadIdx.x;
    const int n = tid >> 5, p = tid & 31;
    __shared__ float Rl[2][NLBL][NLBL + 1];
    __shared__ float tl[NLBL][NLBL + 1];
    const int t0 = blockIdx.x * 8;
    float e[8];
    #pragma unroll
    for (int s = 0; s < 8; ++s) e[s] = logits[(size_t)(t0 + s) * NLBL + n];
    float myt = trans[n * NLBL + p];
    tl[n][p] = myt;
    __syncthreads();
    float tr[NLBL];
    #pragma unroll
    for (int k = 0; k < NLBL; ++k) tr[k] = tl[n][k];
    Rl[0][n][p] = myt + e[0];
    __syncthreads();
    float rn = 0.0f;
    for (int s = 1; s < 8; ++s) {
        const int cur = (s - 1) & 1, nxt = s & 1;
        float v[NLBL];
        #pragma unroll
        for (int k = 0; k < NLBL; ++k) v[k] = tr[k] + Rl[cur][k][p];
        float m = v[0];
        #pragma unroll
        for (int k = 1; k < NLBL; ++k) m = fmaxf(m, v[k]);
        float sum = 0.0f;
        #pragma unroll
        for (int k = 0; k < NLBL; ++k) sum += __expf(v[k] - m);
        rn = e[s] + m + __logf(sum);
        Rl[nxt][n][p] = rn;
        __syncthreads();
    }
    mats[(size_t)blockIdx.x * 1024 + tid] = rn;
}

// 8b. CRF tree level N: block b chains `chunk` consecutive 32x32 matrices.
__global__ __launch_bounds__(1024) void crf_chainN_k(const float* __restrict__ min_,
                                                     float* __restrict__ mout,
                                                     int chunk) {
    const int tid = threadIdx.x;
    const int n = tid >> 5, p = tid & 31;
    __shared__ float Rl[2][NLBL][NLBL + 1];
    __shared__ float Al[2][NLBL][NLBL + 1];
    const size_t base = (size_t)blockIdx.x * chunk;
    float rn = min_[base * 1024 + tid];
    Rl[0][n][p] = rn;
    float anext = min_[(base + 1) * 1024 + tid];
    __syncthreads();
    for (int s = 1; s < chunk; ++s) {
        const int cur = (s - 1) & 1, nxt = s & 1;
        Al[nxt][n][p] = anext;
        if (s + 1 < chunk) anext = min_[(base + s + 1) * 1024 + tid];
        __syncthreads();
        float v[NLBL];
        #pragma unroll
        for (int k = 0; k < NLBL; ++k) v[k] = Al[nxt][n][k] + Rl[cur][k][p];
        float m = v[0];
        #pragma unroll
        for (int k = 1; k < NLBL; ++k) m = fmaxf(m, v[k]);
        float sum = 0.0f;
        #pragma unroll
        for (int k = 0; k < NLBL; ++k) sum += __expf(v[k] - m);
        rn = m + __logf(sum);
        Rl[nxt][n][p] = rn;
        __syncthreads();
    }
    mout[(size_t)blockIdx.x * 1024 + tid] = rn;
}

// 8c. CRF finish: chain last `chunk` matrices, apply alpha0 / trans[SEP] / gold.
__global__ __launch_bounds__(1024) void crf_finish_k(const float* __restrict__ min_,
                                                     const float* __restrict__ trans,
                                                     const float* __restrict__ gold,
                                                     float* __restrict__ out,
                                                     int chunk) {
    const int tid = threadIdx.x;
    const int n = tid >> 5, p = tid & 31;
    __shared__ float Rl[2][NLBL][NLBL + 1];
    __shared__ float Al[2][NLBL][NLBL + 1];
    __shared__ float af[NLBL];
    float rn = min_[tid];
    Rl[0][n][p] = rn;
    float anext = min_[1024 + tid];
    __syncthreads();
    for (int s = 1; s < chunk; ++s) {
        const int cur = (s - 1) & 1, nxt = s & 1;
        Al[nxt][n][p] = anext;
        if (s + 1 < chunk) anext = min_[(size_t)(s + 1) * 1024 + tid];
        __syncthreads();
        float v[NLBL];
        #pragma unroll
        for (int k = 0; k < NLBL; ++k) v[k] = Al[nxt][n][k] + Rl[cur][k][p];
        float m = v[0];
        #pragma unroll
        for (int k = 1; k < NLBL; ++k) m = fmaxf(m, v[k]);
        float sum = 0.0f;
        #pragma unroll
        for (int k = 0; k < NLBL; ++k) sum += __expf(v[k] - m);
        rn = m + __logf(sum);
        Rl[nxt][n][p] = rn;
        __syncthreads();
    }
    // alpha = C ∘ alpha0 ; alpha0[p] = (p==CLS) ? 0 : -1e4
    float val = rn + ((p == CLS_TAG) ? 0.0f : -10000.0f);
    float m = val;
    #pragma unroll
    for (int off = 16; off; off >>= 1) m = fmaxf(m, __shfl_xor(m, off, 32));
    float esum = __expf(val - m);
    #pragma unroll
    for (int off = 16; off; off >>= 1) esum += __shfl_xor(esum, off, 32);
    if (p == 0) af[n] = m + __logf(esum);
    __syncthreads();
    if (tid < NLBL) {
        float f = af[tid] + trans[SEP_TAG * NLBL + tid];
        float mm = f;
        #pragma unroll
        for (int off = 16; off; off >>= 1) mm = fmaxf(mm, __shfl_xor(mm, off, 32));
        float es = __expf(f - mm);
        #pragma unroll
        for (int off = 16; off; off >>= 1) es += __shfl_xor(es, off, 32);
        if (tid == 0) out[0] = mm + __logf(es) - gold[0];
    }
}

// ---------------- launch ----------------

extern "C" void kernel_launch(void* const* d_in, const int* in_sizes, int n_in,
                              void* d_out, int out_size, void* d_ws, size_t ws_size,
                              hipStream_t stream) {
    const int*   ids     = (const int*)d_in[0];
    const int*   target  = (const int*)d_in[2];
    const float* emb     = (const float*)d_in[3];
    const float* w_ih_f  = (const float*)d_in[4];
    const float* w_hh_f  = (const float*)d_in[5];
    const float* b_f     = (const float*)d_in[6];
    const float* w_ih_b  = (const float*)d_in[7];
    const float* w_hh_b  = (const float*)d_in[8];
    const float* b_b     = (const float*)d_in[9];
    const float* w_lin   = (const float*)d_in[10];
    const float* b_lin   = (const float*)d_in[11];
    const float* trans   = (const float*)d_in[12];
    const float* h0      = (const float*)d_in[13];
    const float* c0      = (const float*)d_in[14];
    float* out = (float*)d_out;

    char* ws = (char*)d_ws;
    size_t off = 0;
    float* xbuf   = (float*)(ws + off); off += (size_t)T_LEN * 256 * 4;       // 2 MB
    float* xproj  = (float*)(ws + off); off += (size_t)2 * T_LEN * G4 * 4;    // 16 MB
    float* hs     = (float*)(ws + off); off += (size_t)T_LEN * 512 * 4;       // 4 MB
    float* logits = (float*)(ws + off); off += (size_t)T_LEN * NLBL * 4;      // 256 KB
    float* srow   = (float*)(ws + off); off += (size_t)2 * G4 * 4;            // 8 KB
    float* sh0v   = (float*)(ws + off); off += 16;
    float* gold   = (float*)(ws + off); off += 16;
    int*   hq0    = (int*)(ws + off);   off += (size_t)2 * 64 * 4;
    signed char* wq = (signed char*)(ws + off); off += (size_t)2 * G4 * H2;   // 512 KB
    // CRF mats alias xbuf (dead after gemm_xproj): 256*4KB + 16*4KB < 2 MB
    float* mats1 = xbuf;
    float* mats2 = xbuf + 256 * 1024;

    gather_k<<<T_LEN, 256, 0, stream>>>(ids, emb, xbuf);
    quant_w_k<<<512, 256, 0, stream>>>(w_hh_f, w_hh_b, wq, srow);
    quant_h0_k<<<2, 64, 0, stream>>>(h0, hq0, sh0v);
    gemm_xproj_k<<<dim3(32, 32), 256, 0, stream>>>(xbuf, w_ih_f, w_ih_b, b_f, b_b, xproj);
    lstm_rec_k<<<2, 512, 0, stream>>>(wq, srow, xproj, hq0, sh0v, c0, hs);
    logits_k<<<dim3(256, 2), 128, 0, stream>>>(hs, w_lin, b_lin, logits);
    gold_k<<<1, 256, 0, stream>>>(trans, target, logits, gold);
    crf_chain0_k<<<256, 1024, 0, stream>>>(logits, trans, mats1);
    crf_chainN_k<<<16, 1024, 0, stream>>>(mats1, mats2, 16);
    crf_finish_k<<<1, 1024, 0, stream>>>(mats2, trans, gold, out, 16);
}